// Round 10
// baseline (3678.864 us; speedup 1.0000x reference)
//
#include <hip/hip_runtime.h>
#include <hip/hip_bf16.h>

#define SEQT 2000
#define NB   2048
#define H1   51
#define MROW 16
#define NBLK (NB / MROW)   // 128 blocks
#define PADK 328           // shorts per staged row

typedef float f32x4 __attribute__((ext_vector_type(4)));
typedef short s16x8 __attribute__((ext_vector_type(8)));

__device__ __forceinline__ short f2bf(float f) { __hip_bfloat16 b(f); return *(short*)&b; }
__device__ __forceinline__ float bf2f(short s) { __hip_bfloat16 b; *(short*)&b = s; return (float)b; }
__device__ __forceinline__ float rbf(float f) { return bf2f(f2bf(f)); }
__device__ __forceinline__ float sigf(float x) { return 1.f / (1.f + __expf(-x)); }
__device__ __forceinline__ float tanhfast(float x) { return 1.f - 2.f / (__expf(2.f * x) + 1.f); }

// Staged-vector K-map (cols) and n'=u*4+g N-ordering identical to R9:
//   2u/2u+1: h_hi/h_lo | 102+u: h_hi | 153..155: x_hi,x_lo,x_hi
//   156,157: 1.0 | 160+2u/161+2u: c1_hi/c1_lo | 262+u: c1_hi
// Wave 0: gate tiles 0..6 + x staging. Wave 1: gate tiles 7..12, z-tile in
// fragment slot 6, LSTM3 state. One s_barrier per ts, parity double-buffer.

__global__ void __launch_bounds__(128)
__attribute__((amdgpu_waves_per_eu(1)))
lstm_fused_kernel(const float* __restrict__ input,
                  const float* __restrict__ W_ih1,
                  const float* __restrict__ W_hh1,
                  const float* __restrict__ b_ih1,
                  const float* __restrict__ b_hh1,
                  const float* __restrict__ W_ih3,
                  const float* __restrict__ W_hh3,
                  const float* __restrict__ b_ih3,
                  const float* __restrict__ b_hh3,
                  float* __restrict__ out) {
    const int t = threadIdx.x;
    const int w = t >> 6;          // wave 0..1
    const int lane = t & 63;
    const int iloc = lane & 15, kq = lane >> 4;
    const int r0 = blockIdx.x * MROW;

    __shared__ short Hst[2][MROW * PADK];
    __shared__ float Obuf[2][MROW * 64];

    const int NT = (w == 0) ? 7 : 6;   // gate tiles this wave
    const int tb = (w == 0) ? 0 : 7;

    // ---- A-operand fragments: 7 sets (wave1 slot 6 = z-tile) ----
    s16x8 Wfr[7][5];
#pragma unroll
    for (int i = 0; i < 7; ++i) {
        if (i < NT) {
            const int np = (tb + i) * 16 + iloc;
            const int u = np >> 2, g = np & 3;
            const int n = g * H1 + u;
#pragma unroll
            for (int kt = 0; kt < 5; ++kt) {
                s16x8 bf;
#pragma unroll
                for (int j = 0; j < 8; ++j) {
                    const int k = kt * 32 + kq * 8 + j;
                    float v = 0.f;
                    if (u < H1) {
                        if (k < 102) {
                            v = rbf(W_hh1[n * H1 + (k >> 1)]);
                        } else if (k < 153) {
                            const float wv = W_hh1[n * H1 + (k - 102)];
                            v = wv - rbf(wv);
                        } else if (k == 153 || k == 154) {
                            v = rbf(W_ih1[n]);
                        } else if (k == 155) {
                            const float wv = W_ih1[n];
                            v = wv - rbf(wv);
                        } else if (k == 156) {
                            v = rbf(b_ih1[n] + b_hh1[n]);
                        } else if (k == 157) {
                            const float bv = b_ih1[n] + b_hh1[n];
                            v = bv - rbf(bv);
                        }
                    }
                    bf[j] = f2bf(v);
                }
                Wfr[i][kt] = bf;
            }
        }
    }
    if (w == 1) {   // z-tile: rows g=0..3 = W_ih3 hi/lo, into slot 6
        const int g = iloc;
#pragma unroll
        for (int kt = 0; kt < 5; ++kt) {
            s16x8 bf;
#pragma unroll
            for (int j = 0; j < 8; ++j) {
                const int kz = kt * 32 + kq * 8 + j;   // col - 160
                float v = 0.f;
                if (iloc < 4) {
                    if (kz < 102) {
                        v = rbf(W_ih3[g * H1 + (kz >> 1)]);
                    } else if (kz < 153) {
                        const float wv = W_ih3[g * H1 + (kz - 102)];
                        v = wv - rbf(wv);
                    }
                }
                bf[j] = f2bf(v);
            }
            Wfr[6][kt] = bf;
        }
    }

    const float whh3_0 = W_hh3[0], whh3_1 = W_hh3[1];
    const float whh3_2 = W_hh3[2], whh3_3 = W_hh3[3];
    const float b3_0 = b_ih3[0] + b_hh3[0];
    const float b3_1 = b_ih3[1] + b_hh3[1];
    const float b3_2 = b_ih3[2] + b_hh3[2];
    const float b3_3 = b_ih3[3] + b_hh3[3];

    // ---- LDS init ----
    for (int idx = t; idx < 2 * MROW * PADK; idx += 128)
        ((short*)Hst)[idx] = 0;
    __syncthreads();
    if (t < MROW) {
        const int m = t;
#pragma unroll
        for (int p = 0; p < 2; ++p) {
            Hst[p][m * PADK + 156] = (short)0x3F80;   // 1.0
            Hst[p][m * PADK + 157] = (short)0x3F80;
        }
        const float x0 = input[(size_t)(r0 + m) * SEQT];
        const short xh = f2bf(x0), xl = f2bf(x0 - bf2f(xh));
        Hst[1][m * PADK + 153] = xh;   // window 0 reads parity 1
        Hst[1][m * PADK + 154] = xl;
        Hst[1][m * PADK + 155] = xh;
    }
    float xreg = 0.f;
    if (w == 0 && lane < MROW)
        xreg = input[(size_t)(r0 + lane) * SEQT + 1];
    float c1st[7] = {0.f, 0.f, 0.f, 0.f, 0.f, 0.f, 0.f};
    float h3 = 0.f, c3 = 0.f;   // LSTM3 state (wave 1, lanes 0..15)

#pragma unroll 1
    for (int ts = 0; ts <= SEQT; ++ts) {
        __syncthreads();
        const int rb = (ts + 1) & 1, wb = ts & 1;

        // ---- coalesced dump of finished 64-chunk (8 rows per wave) ----
        if (ts >= 65 && (ts & 63) == 1) {
            const int c = (ts >> 6) - 1;
#pragma unroll
            for (int rep = 0; rep < 8; ++rep) {
                const int row = w * 8 + rep;
                out[(size_t)(r0 + row) * SEQT + c * 64 + lane] =
                    Obuf[c & 1][row * 64 + lane];
            }
        }

        if (ts < SEQT) {
            // ---- B-frags: staged vector cols 0..159 ----
            s16x8 hf[5];
#pragma unroll
            for (int kt = 0; kt < 5; ++kt)
                hf[kt] = *(const s16x8*)&Hst[rb][iloc * PADK + kt * 32 + kq * 8];

            // ---- MFMA + dense lane-local epilogue per gate tile ----
#pragma unroll
            for (int i = 0; i < 7; ++i) {
                if (i < NT) {
                    f32x4 acc = (f32x4){0.f, 0.f, 0.f, 0.f};
#pragma unroll
                    for (int kt = 0; kt < 5; ++kt)
                        acc = __builtin_amdgcn_mfma_f32_16x16x32_bf16(
                            Wfr[i][kt], hf[kt], acc, 0, 0, 0);
                    const int u = (tb + i) * 4 + kq;
                    const int m = iloc;
                    float c1 = c1st[i];
                    c1 = sigf(acc[1]) * c1 + sigf(acc[0]) * tanhfast(acc[2]);
                    c1st[i] = c1;
                    const float h1 = sigf(acc[3]) * tanhfast(c1);
                    if (u < H1) {
                        const short hh = f2bf(h1), hl = f2bf(h1 - bf2f(hh));
                        *(unsigned*)&Hst[wb][m * PADK + 2 * u] =
                            (unsigned)(unsigned short)hh |
                            ((unsigned)(unsigned short)hl << 16);
                        Hst[wb][m * PADK + 102 + u] = hh;
                        const short ch = f2bf(c1), cl = f2bf(c1 - bf2f(ch));
                        *(unsigned*)&Hst[wb][m * PADK + 160 + 2 * u] =
                            (unsigned)(unsigned short)ch |
                            ((unsigned)(unsigned short)cl << 16);
                        Hst[wb][m * PADK + 262 + u] = ch;
                    }
                }
            }

            // ---- x writer (wave 0): stage x(ts+1) ----
            if (w == 0 && lane < MROW) {
                const int m = lane;
                const short xh = f2bf(xreg), xl = f2bf(xreg - bf2f(xh));
                Hst[wb][m * PADK + 153] = xh;
                Hst[wb][m * PADK + 154] = xl;
                Hst[wb][m * PADK + 155] = xh;
                xreg = (ts + 2 < SEQT)
                           ? input[(size_t)(r0 + m) * SEQT + ts + 2] : 0.f;
            }
        }

        // ---- z + LSTM3 for step ts-1 (wave 1; z-tile = Wfr[6]) ----
        if (w == 1 && ts >= 1) {
            s16x8 zf[5];
#pragma unroll
            for (int kt = 0; kt < 5; ++kt)
                zf[kt] = *(const s16x8*)
                    &Hst[rb][iloc * PADK + 160 + kt * 32 + kq * 8];
            f32x4 zacc = (f32x4){0.f, 0.f, 0.f, 0.f};
#pragma unroll
            for (int kt = 0; kt < 5; ++kt)
                zacc = __builtin_amdgcn_mfma_f32_16x16x32_bf16(
                    Wfr[6][kt], zf[kt], zacc, 0, 0, 0);
            if (lane < MROW) {   // lane m holds rows g=0..3 in acc regs
                const int m = lane, s = ts - 1;
                const float gi = zacc[0] + fmaf(whh3_0, h3, b3_0);
                const float gf = zacc[1] + fmaf(whh3_1, h3, b3_1);
                const float gg = zacc[2] + fmaf(whh3_2, h3, b3_2);
                const float go = zacc[3] + fmaf(whh3_3, h3, b3_3);
                c3 = sigf(gf) * c3 + sigf(gi) * tanhfast(gg);
                h3 = sigf(go) * tanhfast(c3);
                Obuf[(s >> 6) & 1][m * 64 + (s & 63)] = c3;
            }
        }
    }

    __syncthreads();
    // tail: steps 1984..1999 (chunk 31, parity 1)
#pragma unroll
    for (int i = 0; i < 2; ++i) {
        const int idx = t + i * 128;
        out[(size_t)(r0 + (idx >> 4)) * SEQT + 1984 + (idx & 15)] =
            Obuf[1][(idx >> 4) * 64 + (idx & 15)];
    }
}

extern "C" void kernel_launch(void* const* d_in, const int* in_sizes, int n_in,
                              void* d_out, int out_size, void* d_ws, size_t ws_size,
                              hipStream_t stream) {
    const float* input = (const float*)d_in[0];
    const float* W_ih1 = (const float*)d_in[1];
    const float* W_hh1 = (const float*)d_in[2];
    const float* b_ih1 = (const float*)d_in[3];
    const float* b_hh1 = (const float*)d_in[4];
    const float* W_ih3 = (const float*)d_in[5];
    const float* W_hh3 = (const float*)d_in[6];
    const float* b_ih3 = (const float*)d_in[7];
    const float* b_hh3 = (const float*)d_in[8];
    float* out = (float*)d_out;

    lstm_fused_kernel<<<NBLK, 128, 0, stream>>>(
        input, W_ih1, W_hh1, b_ih1, b_hh1, W_ih3, W_hh3, b_ih3, b_hh3, out);
}